// Round 2
// baseline (200843.225 us; speedup 1.0000x reference)
//
#include <hip/hip_runtime.h>

#define T_TOTAL 131072
#define SB 32

typedef __attribute__((ext_vector_type(8))) short short8;
typedef __attribute__((ext_vector_type(4))) float f32x4;

__device__ __forceinline__ float sigf(float x) {
  return 1.f / (1.f + __expf(-x));
}
__device__ __forceinline__ float tanhfast(float x) {
  return 1.f - 2.f / (__expf(2.f * x) + 1.f);
}
__device__ __forceinline__ unsigned short f2bf(float x) {
  unsigned u = __float_as_uint(x);
  return (unsigned short)((u + 0x7FFFu + ((u >> 16) & 1u)) >> 16);
}

// ---------- input-projection GEMM, PERMUTED output layout [t][j][g]
// thread tid -> (j = tid>>2, g = tid&3), original row = g*128+j
// out[t*512 + j*4 + g]; stores are coalesced since tid == j*4+g.
template<int K>
__global__ __launch_bounds__(512) void pre_gemm(
    const float* __restrict__ in, const float* __restrict__ W,
    const float* __restrict__ ba, const float* __restrict__ bb,
    float* __restrict__ out)
{
  __shared__ float tile[64 * K];
  const int tid = threadIdx.x;
  const size_t t0 = (size_t)blockIdx.x * 64;
  for (int i = tid; i < 64 * K; i += 512) tile[i] = in[t0 * K + i];
  __syncthreads();
  const int g = tid & 3, jj = tid >> 2;
  const int row = g * 128 + jj;
  const float bias = ba[row] + bb[row];
  float acc[64];
#pragma unroll
  for (int r = 0; r < 64; ++r) acc[r] = 0.f;
  for (int kb = 0; kb < K; kb += 8) {
    float wv[8];
#pragma unroll
    for (int k = 0; k < 8; ++k) wv[k] = W[(size_t)row * K + kb + k];
#pragma unroll
    for (int r = 0; r < 64; ++r) {
#pragma unroll
      for (int k = 0; k < 8; ++k) acc[r] = fmaf(wv[k], tile[r * K + kb + k], acc[r]);
    }
  }
#pragma unroll
  for (int r = 0; r < 64; ++r) out[(t0 + r) * 512 + tid] = acc[r] + bias;
}

// ---------- MFMA-based sequential LSTM recurrence.
// pre: [nsteps][j][g] f32 (x-proj + both biases). hout: [nsteps][128] f32.
// Whh: original [4H][H]. carry: h[128], c[128].
// 8 waves; wave w owns permuted-row tiles rt = 4w..4w+3 (j's w*16..w*16+15).
// A-frag (16x16x32 bf16): row-in-tile = lane&15, k = kc*32 + (lane>>4)*8 + e.
// B replicated across columns: lane reads h[k-octet] only -> D cols identical.
// D: col = lane&15 (replica), row-in-tile = (lane>>4)*4 + reg = 4*(j%4)+gate.
__global__ __launch_bounds__(512) void lstm_rec(
    const float* __restrict__ pre,
    float* __restrict__ hout,
    const float* __restrict__ Whh,
    float* __restrict__ carry,
    int nsteps)
{
  __shared__ __align__(16) float preb[2][SB * 512];          // 128 KB
  __shared__ __align__(16) unsigned short hb[2][128];        // bf16 h, dbuf
  const int tid = threadIdx.x;
  const int l = tid & 63, w = tid >> 6;
  const int ar = l & 15;         // A row-in-tile / D column
  const int q  = l >> 4;         // k-octet / D row-quad
  const int ti_mine = ar & 3;    // which of my wave's 4 tiles this lane finishes
  const int j_mine = (w * 4 + ti_mine) * 4 + q;

  // ---- load Whh into bf16 A-fragments (once)
  short8 af[4][4];  // [tile][kc]
#pragma unroll
  for (int ti = 0; ti < 4; ++ti) {
    const int rp = (w * 4 + ti) * 16 + ar;   // permuted row = 4j+g
    const int jm = rp >> 2, g = rp & 3;
    const float* wr = Whh + (size_t)(g * 128 + jm) * 128 + q * 8;
#pragma unroll
    for (int kc = 0; kc < 4; ++kc) {
      short8 v;
#pragma unroll
      for (int e = 0; e < 8; ++e) v[e] = (short)f2bf(wr[kc * 32 + e]);
      af[ti][kc] = v;
    }
  }

  float c_state = carry[128 + j_mine];
  if (tid < 128) hb[0][tid] = f2bf(carry[tid]);

  // ---- prologue: stage pre block 0 into preb[0]
  {
    const float4* src = reinterpret_cast<const float4*>(pre);
    float4 s0[8];
#pragma unroll
    for (int r = 0; r < 8; ++r) s0[r] = src[r * 512 + tid];
#pragma unroll
    for (int r = 0; r < 8; ++r)
      *reinterpret_cast<float4*>(&preb[0][r * 2048 + tid * 4]) = s0[r];
  }
  __syncthreads();

  const int nb = nsteps / SB;
  float4 sreg[8];
  float hlast = 0.f;

  for (int b = 0; b < nb; ++b) {
    const int pb = b & 1;
    for (int s = 0; s < SB; ++s) {
      const int t = b * SB + s;
      const int cur = t & 1;
      if (s == 0 && b + 1 < nb) {  // issue next-block loads
        const float4* src = reinterpret_cast<const float4*>(pre + (size_t)(b + 1) * SB * 512);
#pragma unroll
        for (int r = 0; r < 8; ++r) sreg[r] = src[r * 512 + tid];
      }
      if (s == 1 && b + 1 < nb) {  // land them in the other LDS buffer
#pragma unroll
        for (int r = 0; r < 8; ++r)
          *reinterpret_cast<float4*>(&preb[pb ^ 1][r * 2048 + tid * 4]) = sreg[r];
      }

      // B fragments: h k-octets, replicated across the 16 columns
      short8 bf[4];
#pragma unroll
      for (int kc = 0; kc < 4; ++kc)
        bf[kc] = *reinterpret_cast<const short8*>(&hb[cur][kc * 32 + q * 8]);

      // acc init = pre (correct only for ti_mine; other tiles' lanes unused)
      const f32x4 p4 = *reinterpret_cast<const f32x4*>(&preb[pb][s * 512 + j_mine * 4]);
      f32x4 acc0 = p4, acc1 = p4, acc2 = p4, acc3 = p4;
#pragma unroll
      for (int kc = 0; kc < 4; ++kc) {
        acc0 = __builtin_amdgcn_mfma_f32_16x16x32_bf16(af[0][kc], bf[kc], acc0, 0, 0, 0);
        acc1 = __builtin_amdgcn_mfma_f32_16x16x32_bf16(af[1][kc], bf[kc], acc1, 0, 0, 0);
        acc2 = __builtin_amdgcn_mfma_f32_16x16x32_bf16(af[2][kc], bf[kc], acc2, 0, 0, 0);
        acc3 = __builtin_amdgcn_mfma_f32_16x16x32_bf16(af[3][kc], bf[kc], acc3, 0, 0, 0);
      }
      f32x4 z = acc0;
      z = (ti_mine == 1) ? acc1 : z;
      z = (ti_mine == 2) ? acc2 : z;
      z = (ti_mine == 3) ? acc3 : z;

      const float ig = sigf(z[0]);
      const float fg = sigf(z[1]);
      const float gg = tanhfast(z[2]);
      const float og = sigf(z[3]);
      c_state = fmaf(fg, c_state, ig * gg);
      const float h = og * tanhfast(c_state);
      hlast = h;
      if (ar < 4) {  // one writer column per tile
        hb[cur ^ 1][j_mine] = f2bf(h);
        hout[(size_t)t * 128 + j_mine] = h;
      }
      __syncthreads();
    }
  }
  if (ar < 4) {
    carry[j_mine] = hlast;
    carry[128 + j_mine] = c_state;
  }
}

// ---------- MLP block: out = LeakyReLU( (AFFINE ? a*in+c : in) @ W^T + b )
template<int KI, int KO, bool AFFINE>
__global__ __launch_bounds__(256) void mlp_block(
    const float* __restrict__ in, const float* __restrict__ W,
    const float* __restrict__ bias, const float* __restrict__ ac,
    float* __restrict__ out, float* __restrict__ part)
{
  constexpr int NR = 256 / KO;
  __shared__ float Wl[KO * KI];
  __shared__ float badj[KO];
  __shared__ float red[2][256];
  const int tid = threadIdx.x;
  const int j = tid % KO, rsub = tid / KO;

  for (int i = tid; i < KO * KI; i += 256) {
    float wv = W[i];
    if constexpr (AFFINE) wv *= ac[i % KI];
    Wl[i] = wv;
  }
  if (tid < KO) {
    float s = bias[tid];
    if constexpr (AFFINE) {
      for (int k = 0; k < KI; ++k) s = fmaf(W[tid * KI + k], ac[KI + k], s);
    }
    badj[tid] = s;
  }
  __syncthreads();

  const size_t t0 = (size_t)blockIdx.x * 64;
  float psum = 0.f, psq = 0.f;
  for (int r = rsub; r < 64; r += NR) {
    const float* row = in + (t0 + r) * KI;
    float acc = badj[j];
#pragma unroll
    for (int k = 0; k < KI; ++k) acc = fmaf(Wl[j * KI + k], row[k], acc);
    const float y = acc >= 0.f ? acc : 0.01f * acc;
    out[(t0 + r) * KO + j] = y;
    psum += y; psq += y * y;
  }
  red[0][tid] = psum; red[1][tid] = psq;
  __syncthreads();
  if (tid < KO) {
    float s = 0.f, qq = 0.f;
#pragma unroll
    for (int rr = 0; rr < NR; ++rr) { s += red[0][rr * KO + tid]; qq += red[1][rr * KO + tid]; }
    part[(size_t)blockIdx.x * (2 * KO) + tid] = s;
    part[(size_t)blockIdx.x * (2 * KO) + KO + tid] = qq;
  }
}

__global__ __launch_bounds__(64) void bn_reduce(
    const float* __restrict__ part, const float* __restrict__ gamma,
    const float* __restrict__ beta, float* __restrict__ ac,
    int nblk, int KO, float invT)
{
  const int j = threadIdx.x;
  if (j >= KO) return;
  float s = 0.f, q = 0.f;
  for (int b = 0; b < nblk; ++b) {
    s += part[(size_t)b * 2 * KO + j];
    q += part[(size_t)b * 2 * KO + KO + j];
  }
  const float m = s * invT;
  const float v = q * invT - m * m;
  const float inv = 1.f / sqrtf(v + 1e-5f);
  const float a = gamma[j] * inv;
  ac[j] = a;
  ac[KO + j] = beta[j] - m * a;
}

__global__ __launch_bounds__(256) void final_out(
    const float* __restrict__ y3, const float* __restrict__ wo,
    const float* __restrict__ bo, const float* __restrict__ ac,
    float* __restrict__ out)
{
  const size_t t = (size_t)blockIdx.x * 256 + threadIdx.x;
  float acc = bo[0];
#pragma unroll
  for (int k = 0; k < 16; ++k) acc = fmaf(wo[k], ac[16 + k], acc);
#pragma unroll
  for (int k = 0; k < 16; ++k) acc = fmaf(wo[k] * ac[k], y3[t * 16 + k], acc);
  out[t] = acc;
}

extern "C" void kernel_launch(void* const* d_in, const int* in_sizes, int n_in,
                              void* d_out, int out_size, void* d_ws, size_t ws_size,
                              hipStream_t stream) {
  const float* x    = (const float*)d_in[0];
  const float* Wih0 = (const float*)d_in[1];
  const float* Whh0 = (const float*)d_in[2];
  const float* bih0 = (const float*)d_in[3];
  const float* bhh0 = (const float*)d_in[4];
  const float* Wih1 = (const float*)d_in[5];
  const float* Whh1 = (const float*)d_in[6];
  const float* bih1 = (const float*)d_in[7];
  const float* bhh1 = (const float*)d_in[8];
  const float* w1 = (const float*)d_in[9];  const float* b1 = (const float*)d_in[10];
  const float* g1 = (const float*)d_in[11]; const float* be1 = (const float*)d_in[12];
  const float* w2 = (const float*)d_in[13]; const float* b2 = (const float*)d_in[14];
  const float* g2 = (const float*)d_in[15]; const float* be2 = (const float*)d_in[16];
  const float* w3 = (const float*)d_in[17]; const float* b3 = (const float*)d_in[18];
  const float* g3 = (const float*)d_in[19]; const float* be3 = (const float*)d_in[20];
  const float* wo = (const float*)d_in[21]; const float* bo = (const float*)d_in[22];
  float* out = (float*)d_out;

  const int T = T_TOTAL;
  const size_t MB = 1ull << 20;

  int CH = 16384;
  const size_t fixed = 4 * MB + (64 + 32 + 16 + 8) * MB;
  while (CH > 1024 && fixed + (size_t)CH * 4608 > ws_size) CH >>= 1;
  const int NC = T / CH;

  char* w8 = (char*)d_ws;
  float* carry0 = (float*)(w8);
  float* carry1 = (float*)(w8 + 1024);
  float* ac1    = (float*)(w8 + 4096);
  float* ac2    = (float*)(w8 + 4096 + 1024);
  float* ac3    = (float*)(w8 + 4096 + 2048);
  float* part1  = (float*)(w8 + 64 * 1024);
  float* part2  = (float*)(w8 + 64 * 1024 + MB);
  float* part3  = (float*)(w8 + 64 * 1024 + MB + MB / 2);
  char* big = w8 + 4 * MB;
  float* h1   = (float*)(big);
  float* y1   = (float*)(big + 64 * MB);
  float* y2   = (float*)(big + 96 * MB);
  float* y3   = (float*)(big + 112 * MB);
  float* pre0 = (float*)(big + 120 * MB);
  float* pre1 = pre0 + (size_t)CH * 512;
  float* h0b  = pre1 + (size_t)CH * 512;

  hipMemsetAsync(d_ws, 0, 2048, stream);

  for (int c = 0; c < NC; ++c) {
    pre_gemm<8><<<CH / 64, 512, 0, stream>>>(x + (size_t)c * CH * 8, Wih0, bih0, bhh0, pre0);
    lstm_rec<<<1, 512, 0, stream>>>(pre0, h0b, Whh0, carry0, CH);
    pre_gemm<128><<<CH / 64, 512, 0, stream>>>(h0b, Wih1, bih1, bhh1, pre1);
    lstm_rec<<<1, 512, 0, stream>>>(pre1, h1 + (size_t)c * CH * 128, Whh1, carry1, CH);
  }

  mlp_block<128, 64, false><<<T / 64, 256, 0, stream>>>(h1, w1, b1, nullptr, y1, part1);
  bn_reduce<<<1, 64, 0, stream>>>(part1, g1, be1, ac1, T / 64, 64, 1.f / T);
  mlp_block<64, 32, true><<<T / 64, 256, 0, stream>>>(y1, w2, b2, ac1, y2, part2);
  bn_reduce<<<1, 64, 0, stream>>>(part2, g2, be2, ac2, T / 64, 32, 1.f / T);
  mlp_block<32, 16, true><<<T / 64, 256, 0, stream>>>(y2, w3, b3, ac2, y3, part3);
  bn_reduce<<<1, 64, 0, stream>>>(part3, g3, be3, ac3, T / 64, 16, 1.f / T);
  final_out<<<T / 256, 256, 0, stream>>>(y3, wo, bo, ac3, out);
}

// Round 3
// 175740.649 us; speedup vs baseline: 1.1428x; 1.1428x over previous
//
#include <hip/hip_runtime.h>

#define T_TOTAL 131072
#define SB 32

typedef __attribute__((ext_vector_type(8))) short short8;
typedef __attribute__((ext_vector_type(8))) unsigned short ushort8;
typedef __attribute__((ext_vector_type(4))) float f32x4;

__device__ __forceinline__ float sigf(float x) {
  return 1.f / (1.f + __expf(-x));
}
__device__ __forceinline__ float tanhfast(float x) {
  return 1.f - 2.f / (__expf(2.f * x) + 1.f);
}
__device__ __forceinline__ unsigned short f2bf(float x) {
  unsigned u = __float_as_uint(x);
  return (unsigned short)((u + 0x7FFFu + ((u >> 16) & 1u)) >> 16);
}
__device__ __forceinline__ float bf2f(unsigned short u) {
  return __uint_as_float(((unsigned)u) << 16);
}
__device__ __forceinline__ float ld_f32(const float* p) { return *p; }
__device__ __forceinline__ float ld_f32(const unsigned short* p) { return bf2f(*p); }

// async global->LDS, 16B per lane, LDS dest = uniform base + lane*16
__device__ __forceinline__ void load_lds16(const void* g, void* l) {
  __builtin_amdgcn_global_load_lds(
      (const __attribute__((address_space(1))) void*)g,
      (__attribute__((address_space(3))) void*)l, 16, 0, 0);
}

// ---------- input-projection GEMM, PERMUTED output layout [t][j][g]
// thread tid -> (j = tid>>2, g = tid&3), original row = g*128+j
template<int K, typename TI>
__global__ __launch_bounds__(512) void pre_gemm(
    const TI* __restrict__ in, const float* __restrict__ W,
    const float* __restrict__ ba, const float* __restrict__ bb,
    float* __restrict__ out)
{
  __shared__ float tile[64 * K];
  const int tid = threadIdx.x;
  const size_t t0 = (size_t)blockIdx.x * 64;
  for (int i = tid; i < 64 * K; i += 512) tile[i] = ld_f32(&in[t0 * K + i]);
  __syncthreads();
  const int g = tid & 3, jj = tid >> 2;
  const int row = g * 128 + jj;
  const float bias = ba[row] + bb[row];
  float acc[64];
#pragma unroll
  for (int r = 0; r < 64; ++r) acc[r] = 0.f;
  for (int kb = 0; kb < K; kb += 8) {
    float wv[8];
#pragma unroll
    for (int k = 0; k < 8; ++k) wv[k] = W[(size_t)row * K + kb + k];
#pragma unroll
    for (int r = 0; r < 64; ++r) {
#pragma unroll
      for (int k = 0; k < 8; ++k) acc[r] = fmaf(wv[k], tile[r * K + kb + k], acc[r]);
    }
  }
#pragma unroll
  for (int r = 0; r < 64; ++r) out[(t0 + r) * 512 + tid] = acc[r] + bias;
}

// ---------- MFMA sequential LSTM recurrence, drain-free step loop.
// pre: [nsteps][j][g] f32. hout: [nsteps][128] bf16. Whh: [4H][H] f32.
// carry: h f32[128], c f32[128].
// 8 waves; wave w owns tiles 4w..4w+3 (units 16w..16w+15).
__global__ __launch_bounds__(512) void lstm_rec(
    const float* __restrict__ pre,
    unsigned short* __restrict__ hout,
    const float* __restrict__ Whh,
    float* __restrict__ carry,
    int nsteps)
{
  __shared__ __align__(16) float preb[2][SB * 512];              // 128 KB
  __shared__ __align__(16) unsigned short hhist[2][SB][128];     // 16 KB
  const int tid = threadIdx.x;
  const int l = tid & 63, w = tid >> 6;
  const int ar = l & 15;         // A row-in-tile / D column
  const int q  = l >> 4;         // k-octet / D row-quad
  const int ti_mine = ar & 3;
  const int j_mine = (w * 4 + ti_mine) * 4 + q;

  // ---- Whh -> bf16 A-fragments (once)
  short8 af[4][4];
#pragma unroll
  for (int ti = 0; ti < 4; ++ti) {
    const int rp = (w * 4 + ti) * 16 + ar;   // permuted row = 4j+g
    const int jm = rp >> 2, g = rp & 3;
    const float* wr = Whh + (size_t)(g * 128 + jm) * 128 + q * 8;
#pragma unroll
    for (int kc = 0; kc < 4; ++kc) {
      short8 v;
#pragma unroll
      for (int e = 0; e < 8; ++e) v[e] = (short)f2bf(wr[kc * 32 + e]);
      af[ti][kc] = v;
    }
  }

  float c_state = carry[128 + j_mine];
  if (tid < 128) hhist[1][SB - 1][tid] = f2bf(carry[tid]);

  // ---- prologue: stage pre block 0 into preb[0] via global_load_lds
#pragma unroll
  for (int r = 0; r < 8; ++r)
    load_lds16(pre + r * 2048 + w * 256 + l * 4, &preb[0][r * 2048 + w * 256]);
  asm volatile("s_waitcnt vmcnt(0) lgkmcnt(0)" ::: "memory");
  __builtin_amdgcn_sched_barrier(0);
  __builtin_amdgcn_s_barrier();
  __builtin_amdgcn_sched_barrier(0);

  const int nb = nsteps / SB;
  float hlast = 0.f;

  for (int b = 0; b < nb; ++b) {
    const int pb = b & 1;
    // issue next-block staging (async; drained once at block end)
    if (b + 1 < nb) {
      const float* src = pre + (size_t)(b + 1) * SB * 512;
#pragma unroll
      for (int r = 0; r < 8; ++r)
        load_lds16(src + r * 2048 + w * 256 + l * 4, &preb[pb ^ 1][r * 2048 + w * 256]);
    }
    // flush previous block's h history (stores never waited mid-loop)
    if (b > 0) {
      const ushort8 hv = *reinterpret_cast<const ushort8*>(&hhist[pb ^ 1][0][0] + tid * 8);
      *reinterpret_cast<ushort8*>(hout + (size_t)(b - 1) * SB * 128 + tid * 8) = hv;
    }

    for (int s = 0; s < SB; ++s) {
      const unsigned short* hrow = (s == 0) ? hhist[pb ^ 1][SB - 1] : hhist[pb][s - 1];
      short8 bf[4];
#pragma unroll
      for (int kc = 0; kc < 4; ++kc)
        bf[kc] = *reinterpret_cast<const short8*>(hrow + kc * 32 + q * 8);

      const f32x4 p4 = *reinterpret_cast<const f32x4*>(&preb[pb][s * 512 + j_mine * 4]);
      f32x4 acc0 = p4, acc1 = p4, acc2 = p4, acc3 = p4;
#pragma unroll
      for (int kc = 0; kc < 4; ++kc) {
        acc0 = __builtin_amdgcn_mfma_f32_16x16x32_bf16(af[0][kc], bf[kc], acc0, 0, 0, 0);
        acc1 = __builtin_amdgcn_mfma_f32_16x16x32_bf16(af[1][kc], bf[kc], acc1, 0, 0, 0);
        acc2 = __builtin_amdgcn_mfma_f32_16x16x32_bf16(af[2][kc], bf[kc], acc2, 0, 0, 0);
        acc3 = __builtin_amdgcn_mfma_f32_16x16x32_bf16(af[3][kc], bf[kc], acc3, 0, 0, 0);
      }
      f32x4 z = acc0;
      z = (ti_mine == 1) ? acc1 : z;
      z = (ti_mine == 2) ? acc2 : z;
      z = (ti_mine == 3) ? acc3 : z;

      const float ig = sigf(z[0]);
      const float fg = sigf(z[1]);
      const float gg = tanhfast(z[2]);
      const float og = sigf(z[3]);
      c_state = fmaf(fg, c_state, ig * gg);
      const float h = og * tanhfast(c_state);
      hlast = h;
      if (ar < 4) hhist[pb][s][j_mine] = f2bf(h);

      asm volatile("s_waitcnt lgkmcnt(0)" ::: "memory");
      __builtin_amdgcn_sched_barrier(0);
      __builtin_amdgcn_s_barrier();
      __builtin_amdgcn_sched_barrier(0);
    }

    // block end: my async loads for b+1 must be in LDS before anyone reads them
    asm volatile("s_waitcnt vmcnt(0)" ::: "memory");
    __builtin_amdgcn_sched_barrier(0);
    __builtin_amdgcn_s_barrier();
    __builtin_amdgcn_sched_barrier(0);
  }

  // epilogue: flush last block's history, write carry
  {
    const int pb = (nb - 1) & 1;
    const ushort8 hv = *reinterpret_cast<const ushort8*>(&hhist[pb][0][0] + tid * 8);
    *reinterpret_cast<ushort8*>(hout + (size_t)(nb - 1) * SB * 128 + tid * 8) = hv;
  }
  if (ar < 4) {
    carry[j_mine] = hlast;
    carry[128 + j_mine] = c_state;
  }
}

// ---------- MLP block: out = LeakyReLU( (AFFINE ? a*in+c : in) @ W^T + b )
template<int KI, int KO, bool AFFINE, typename TI>
__global__ __launch_bounds__(256) void mlp_block(
    const TI* __restrict__ in, const float* __restrict__ W,
    const float* __restrict__ bias, const float* __restrict__ ac,
    float* __restrict__ out, float* __restrict__ part)
{
  constexpr int NR = 256 / KO;
  __shared__ float Wl[KO * KI];
  __shared__ float badj[KO];
  __shared__ float red[2][256];
  const int tid = threadIdx.x;
  const int j = tid % KO, rsub = tid / KO;

  for (int i = tid; i < KO * KI; i += 256) {
    float wv = W[i];
    if constexpr (AFFINE) wv *= ac[i % KI];
    Wl[i] = wv;
  }
  if (tid < KO) {
    float s = bias[tid];
    if constexpr (AFFINE) {
      for (int k = 0; k < KI; ++k) s = fmaf(W[tid * KI + k], ac[KI + k], s);
    }
    badj[tid] = s;
  }
  __syncthreads();

  const size_t t0 = (size_t)blockIdx.x * 64;
  float psum = 0.f, psq = 0.f;
  for (int r = rsub; r < 64; r += NR) {
    const TI* row = in + (t0 + r) * KI;
    float acc = badj[j];
#pragma unroll
    for (int k = 0; k < KI; ++k) acc = fmaf(Wl[j * KI + k], ld_f32(&row[k]), acc);
    const float y = acc >= 0.f ? acc : 0.01f * acc;
    out[(t0 + r) * KO + j] = y;
    psum += y; psq += y * y;
  }
  red[0][tid] = psum; red[1][tid] = psq;
  __syncthreads();
  if (tid < KO) {
    float s = 0.f, qq = 0.f;
#pragma unroll
    for (int rr = 0; rr < NR; ++rr) { s += red[0][rr * KO + tid]; qq += red[1][rr * KO + tid]; }
    part[(size_t)blockIdx.x * (2 * KO) + tid] = s;
    part[(size_t)blockIdx.x * (2 * KO) + KO + tid] = qq;
  }
}

__global__ __launch_bounds__(64) void bn_reduce(
    const float* __restrict__ part, const float* __restrict__ gamma,
    const float* __restrict__ beta, float* __restrict__ ac,
    int nblk, int KO, float invT)
{
  const int j = threadIdx.x;
  if (j >= KO) return;
  float s = 0.f, q = 0.f;
  for (int b = 0; b < nblk; ++b) {
    s += part[(size_t)b * 2 * KO + j];
    q += part[(size_t)b * 2 * KO + KO + j];
  }
  const float m = s * invT;
  const float v = q * invT - m * m;
  const float inv = 1.f / sqrtf(v + 1e-5f);
  const float a = gamma[j] * inv;
  ac[j] = a;
  ac[KO + j] = beta[j] - m * a;
}

__global__ __launch_bounds__(256) void final_out(
    const float* __restrict__ y3, const float* __restrict__ wo,
    const float* __restrict__ bo, const float* __restrict__ ac,
    float* __restrict__ out)
{
  const size_t t = (size_t)blockIdx.x * 256 + threadIdx.x;
  float acc = bo[0];
#pragma unroll
  for (int k = 0; k < 16; ++k) acc = fmaf(wo[k], ac[16 + k], acc);
#pragma unroll
  for (int k = 0; k < 16; ++k) acc = fmaf(wo[k] * ac[k], y3[t * 16 + k], acc);
  out[t] = acc;
}

extern "C" void kernel_launch(void* const* d_in, const int* in_sizes, int n_in,
                              void* d_out, int out_size, void* d_ws, size_t ws_size,
                              hipStream_t stream) {
  const float* x    = (const float*)d_in[0];
  const float* Wih0 = (const float*)d_in[1];
  const float* Whh0 = (const float*)d_in[2];
  const float* bih0 = (const float*)d_in[3];
  const float* bhh0 = (const float*)d_in[4];
  const float* Wih1 = (const float*)d_in[5];
  const float* Whh1 = (const float*)d_in[6];
  const float* bih1 = (const float*)d_in[7];
  const float* bhh1 = (const float*)d_in[8];
  const float* w1 = (const float*)d_in[9];  const float* b1 = (const float*)d_in[10];
  const float* g1 = (const float*)d_in[11]; const float* be1 = (const float*)d_in[12];
  const float* w2 = (const float*)d_in[13]; const float* b2 = (const float*)d_in[14];
  const float* g2 = (const float*)d_in[15]; const float* be2 = (const float*)d_in[16];
  const float* w3 = (const float*)d_in[17]; const float* b3 = (const float*)d_in[18];
  const float* g3 = (const float*)d_in[19]; const float* be3 = (const float*)d_in[20];
  const float* wo = (const float*)d_in[21]; const float* bo = (const float*)d_in[22];
  float* out = (float*)d_out;

  const int T = T_TOTAL;
  const size_t MB = 1ull << 20;

  // fixed = 4MB stats + h1(32MB bf16) + y1(32MB) + y2(16MB) + y3(8MB) = 92MB
  // per-CH = pre0+pre1 (4096*CH) + h0b (256*CH)
  int CH = 16384;
  const size_t fixed = 4 * MB + 88 * MB;
  while (CH > 1024 && fixed + (size_t)CH * 4352 > ws_size) CH >>= 1;
  const int NC = T / CH;

  char* w8 = (char*)d_ws;
  float* carry0 = (float*)(w8);
  float* carry1 = (float*)(w8 + 1024);
  float* ac1    = (float*)(w8 + 4096);
  float* ac2    = (float*)(w8 + 4096 + 1024);
  float* ac3    = (float*)(w8 + 4096 + 2048);
  float* part1  = (float*)(w8 + 64 * 1024);
  float* part2  = (float*)(w8 + 64 * 1024 + MB);
  float* part3  = (float*)(w8 + 64 * 1024 + MB + MB / 2);
  char* big = w8 + 4 * MB;
  unsigned short* h1 = (unsigned short*)(big);          // [T,128] bf16, 32MB
  float* y1   = (float*)(big + 32 * MB);                // [T,64]  32MB
  float* y2   = (float*)(big + 64 * MB);                // [T,32]  16MB
  float* y3   = (float*)(big + 80 * MB);                // [T,16]   8MB
  float* pre0 = (float*)(big + 88 * MB);                // [CH,512] f32
  float* pre1 = pre0 + (size_t)CH * 512;                // [CH,512] f32
  unsigned short* h0b = (unsigned short*)(pre1 + (size_t)CH * 512);  // [CH,128] bf16

  hipMemsetAsync(d_ws, 0, 2048, stream);

  for (int c = 0; c < NC; ++c) {
    pre_gemm<8, float><<<CH / 64, 512, 0, stream>>>(x + (size_t)c * CH * 8, Wih0, bih0, bhh0, pre0);
    lstm_rec<<<1, 512, 0, stream>>>(pre0, h0b, Whh0, carry0, CH);
    pre_gemm<128, unsigned short><<<CH / 64, 512, 0, stream>>>(h0b, Wih1, bih1, bhh1, pre1);
    lstm_rec<<<1, 512, 0, stream>>>(pre1, h1 + (size_t)c * CH * 128, Whh1, carry1, CH);
  }

  mlp_block<128, 64, false, unsigned short><<<T / 64, 256, 0, stream>>>(h1, w1, b1, nullptr, y1, part1);
  bn_reduce<<<1, 64, 0, stream>>>(part1, g1, be1, ac1, T / 64, 64, 1.f / T);
  mlp_block<64, 32, true, float><<<T / 64, 256, 0, stream>>>(y1, w2, b2, ac1, y2, part2);
  bn_reduce<<<1, 64, 0, stream>>>(part2, g2, be2, ac2, T / 64, 32, 1.f / T);
  mlp_block<32, 16, true, float><<<T / 64, 256, 0, stream>>>(y2, w3, b3, ac2, y3, part3);
  bn_reduce<<<1, 64, 0, stream>>>(part3, g3, be3, ac3, T / 64, 16, 1.f / T);
  final_out<<<T / 256, 256, 0, stream>>>(y3, wo, bo, ac3, out);
}